// Round 11
// baseline (389.533 us; speedup 1.0000x reference)
//
#include <hip/hip_runtime.h>
#include <hip/hip_bf16.h>
#include <stdint.h>

#define VOCAB 30000
#define EMBED 256
#define HID   128
#define BB    256
#define TT    512
#define G4    512        // gate columns per direction
#define GWH   1024       // f16 columns in EW2 ([dir][u][g] packed)

typedef _Float16 f16x8 __attribute__((ext_vector_type(8)));
typedef _Float16 f16x4 __attribute__((ext_vector_type(4)));
typedef float    f32x4 __attribute__((ext_vector_type(4)));

// gate scales folded into EW and U at build time:
//   i,f,o : z' = -log2(e)  * z   -> sigm = rcp(1 + exp2(z'))
//   g     : z' = +2log2(e) * z   -> tanh = 1 - 2*rcp(1 + exp2(z'))
#define S_IFO (-1.4426950408889634f)
#define S_G   ( 2.8853900817779268f)

__device__ __forceinline__ float fexp2(float x){
#if __has_builtin(__builtin_amdgcn_exp2f)
  return __builtin_amdgcn_exp2f(x);
#else
  return exp2f(x);
#endif
}
__device__ __forceinline__ float frcp(float x){
#if __has_builtin(__builtin_amdgcn_rcpf)
  return __builtin_amdgcn_rcpf(x);
#else
  return 1.0f/x;
#endif
}
__device__ __forceinline__ float sigm_p(float zp){          // zp pre-scaled
  return frcp(1.0f + fexp2(zp));
}
__device__ __forceinline__ float tanh_p(float zp){          // zp pre-scaled
  return 1.0f - 2.0f*frcp(1.0f + fexp2(zp));
}
__device__ __forceinline__ float tanh_rt(float x){          // runtime tanh
  return 1.0f - 2.0f*frcp(1.0f + fexp2(S_G*x));
}

// ---------------------------------------------------------------------------
// Kernel 1: EW2[v][dirc*512 + u*4 + g] = f16( gsc[g] * (emb[v]@Wcol + b) )
// ---------------------------------------------------------------------------
__global__ __launch_bounds__(256, 4) void embw_mfma(
    const float* __restrict__ emb,
    const float* __restrict__ Wf, const float* __restrict__ Wb,
    const float* __restrict__ bf, const float* __restrict__ bb,
    _Float16* __restrict__ EW)
{
  __shared__ _Float16 As[64*EMBED];   // 32 KB
  const int tid  = threadIdx.x;
  const int l    = tid & 63;
  const int w    = tid >> 6;
  const int r0   = blockIdx.x * 64;
  const int dirc = blockIdx.y >> 3;
  const int u0   = (blockIdx.y & 7) * 16;
  const int nr   = min(64, VOCAB - r0);

  const float4* asrc = (const float4*)(emb + (size_t)r0*EMBED);
  for (int i = tid; i < nr*(EMBED/4); i += 256){
    float4 v = asrc[i];
    const int row = i >> 6;
    const int kc  = (i & 63) * 4;
    const int ks  = kc ^ ((row & 7) << 3);
    _Float16* dst = &As[row*EMBED + ks];
    dst[0]=(_Float16)v.x; dst[1]=(_Float16)v.y;
    dst[2]=(_Float16)v.z; dst[3]=(_Float16)v.w;
  }
  __syncthreads();

  const int cl = w*16 + (l & 15);
  const int ul = cl >> 2;             // 0..15
  const int g  = cl & 3;              // gate
  const int cg = g*128 + u0 + ul;     // original column in [0,512)
  const float* Wsrc = (dirc ? Wb : Wf) + cg;
  const int kg = (l >> 4) * 8;

  f32x4 acc[4] = {{0,0,0,0},{0,0,0,0},{0,0,0,0},{0,0,0,0}};

  for (int kk = 0; kk < EMBED/32; ++kk){
    const int kb = kk*32 + kg;
    f16x8 bfrag;
    #pragma unroll
    for (int j = 0; j < 8; ++j)
      bfrag[j] = (_Float16)Wsrc[(size_t)(kb + j)*G4];
    #pragma unroll
    for (int m = 0; m < 4; ++m){
      const int row = m*16 + (l & 15);
      const int ks  = kb ^ ((row & 7) << 3);
      f16x8 afrag = *(const f16x8*)&As[row*EMBED + ks];
      acc[m] = __builtin_amdgcn_mfma_f32_16x16x32_f16(afrag, bfrag, acc[m], 0, 0, 0);
    }
  }

  const float bv  = (dirc ? bb : bf)[cg];
  const float gsc = (g == 2) ? S_G : S_IFO;
  const int   co  = dirc*512 + (u0 + ul)*4 + g;    // f16 col in EW2
  #pragma unroll
  for (int m = 0; m < 4; ++m){
    #pragma unroll
    for (int r = 0; r < 4; ++r){
      const int vrow = r0 + m*16 + (l >> 4)*4 + r;
      if (vrow < VOCAB)
        EW[(size_t)vrow*GWH + co] = (_Float16)((acc[m][r] + bv) * gsc);
    }
  }
}

// ---------------------------------------------------------------------------
// Kernel 2: recurrence. Round-10 + (1) tokens via GLOBAL loads (vmcnt domain;
// the pre-barrier lgkmcnt(0) no longer waits on token reads) with a 4-step
// register pipeline, (2) MFMA chains depth 4 -> 2 (aP/aQ, persistent-garbage
// accs, only aQ[g][0] re-zeroed). Block = 2 batches x 1 dir, grid 256.
// ---------------------------------------------------------------------------
__global__ __launch_bounds__(512, 2) void lstm_r11(
    const int*      __restrict__ tokens,
    const _Float16* __restrict__ EW,
    const float*    __restrict__ Ufw, const float* __restrict__ Ubw,
    float* __restrict__ out)
{
  __shared__ _Float16 h_lds[2][320];   // batch0 @ f16 idx 0, batch1 @ 160 (pad)

  const int tid = threadIdx.x;
  const int l   = tid & 63;
  const int w   = tid >> 6;               // wave 0..7
  const int lr  = l & 15;
  const int hi  = l >> 4;
  const int dir = blockIdx.x & 1;
  const int b0  = (blockIdx.x >> 1) * 2;

  if (tid < 640) ((_Float16*)h_lds)[tid] = (_Float16)0.f;
  __syncthreads();

  // ---- resident U B-fragments (pre-scaled): ub[kt][gate], 64 VGPRs ----
  const float* U = dir ? Ubw : Ufw;
  f16x8 ub[4][4];
  #pragma unroll
  for (int kt = 0; kt < 4; ++kt){
    #pragma unroll
    for (int g = 0; g < 4; ++g){
      const int   col = g*128 + w*16 + lr;
      const float gs  = (g == 2) ? S_G : S_IFO;
      f16x8 f;
      #pragma unroll
      for (int j = 0; j < 8; ++j)
        f[j] = (_Float16)(U[(size_t)(kt*32 + hi*8 + j)*G4 + col] * gs);
      ub[kt][g] = f;
    }
  }

  const int  bsel = (l >> 2) & 1;      // A-row -> batch
  const bool act  = (l < 32);
  const int  q    = hi & 1;            // batch (lanes 0-31); 32-63 mirror
  const int  u    = w*16 + lr;         // hidden unit

  float creg = 0.f, hfin = 0.f;
  const _Float16* ebase = EW + dir*512 + u*4;
  const int* tokq = tokens + (size_t)(b0+q)*TT;   // GLOBAL token stream

  // step s -> time index (clamped)
  #define TIDX(S) ({ int ss_ = (S); ss_ = ss_ < TT ? ss_ : TT-1;             \
                     dir ? (TT-1-ss_) : ss_; })

  // persistent accumulators: rows 1-3 (and aQ row 0 garbage) never read raw
  f32x4 aP[4], aQ[4];
  #pragma unroll
  for (int g = 0; g < 4; ++g){ aP[g]=(f32x4){0,0,0,0}; aQ[g]=(f32x4){0,0,0,0}; }

  // ---- prologue pipeline (act lanes): xw for steps 0/1; tokens for 2/3 ----
  int tkA = 0, tkB = 0;
  f16x4 xwA = {0,0,0,0}, xwB = {0,0,0,0};
  if (act){
    xwA = *(const f16x4*)(ebase + (size_t)tokq[TIDX(0)]*GWH);
    xwB = *(const f16x4*)(ebase + (size_t)tokq[TIDX(1)]*GWH);
    tkA = tokq[TIDX(2)];
    tkB = tokq[TIDX(3)];
  }

  #define STEP(XW, TK, SCUR, CUR)                                            \
  {                                                                          \
    const int t_ = dir ? (TT-1-(SCUR)) : (SCUR);                             \
    f16x8 ha[4];                                                             \
    _Pragma("unroll")                                                        \
    for (int kt = 0; kt < 4; ++kt)                                           \
      ha[kt] = *(const f16x8*)&h_lds[CUR][bsel*160 + kt*32 + hi*8];          \
    _Pragma("unroll")                                                        \
    for (int g = 0; g < 4; ++g){ aP[g][0] = (float)XW[g]; aQ[g][0] = 0.f; }  \
    if (act){                                                                \
      const _Float16* ad_ = ebase + (size_t)TK*GWH;  /* TK = token(SCUR+2) */\
      XW = *(const f16x4*)ad_;                       /* xw for SCUR+2     */ \
      TK = tokq[TIDX((SCUR)+4)];                     /* token for SCUR+4  */ \
    }                                                                        \
    _Pragma("unroll")                                                        \
    for (int g = 0; g < 4; ++g)                                              \
      aP[g] = __builtin_amdgcn_mfma_f32_16x16x32_f16(ha[0], ub[0][g], aP[g], 0,0,0); \
    _Pragma("unroll")                                                        \
    for (int g = 0; g < 4; ++g)                                              \
      aQ[g] = __builtin_amdgcn_mfma_f32_16x16x32_f16(ha[2], ub[2][g], aQ[g], 0,0,0); \
    _Pragma("unroll")                                                        \
    for (int g = 0; g < 4; ++g)                                              \
      aP[g] = __builtin_amdgcn_mfma_f32_16x16x32_f16(ha[1], ub[1][g], aP[g], 0,0,0); \
    _Pragma("unroll")                                                        \
    for (int g = 0; g < 4; ++g)                                              \
      aQ[g] = __builtin_amdgcn_mfma_f32_16x16x32_f16(ha[3], ub[3][g], aQ[g], 0,0,0); \
    if (act){                                                                \
      const float si = sigm_p(aP[0][0] + aQ[0][0]);                          \
      const float sf = sigm_p(aP[1][0] + aQ[1][0]);                          \
      const float tg = tanh_p(aP[2][0] + aQ[2][0]);                          \
      const float so = sigm_p(aP[3][0] + aQ[3][0]);                          \
      const float cn = sf*creg + si*tg;                                      \
      creg = cn;                                                             \
      const float hh = so*tanh_rt(cn);                                       \
      hfin = hh;                                                             \
      h_lds[(CUR)^1][q*160 + u] = (_Float16)hh;                              \
      out[((size_t)(b0+q)*TT + t_)*(2*HID) + (size_t)dir*HID + u] = hh;      \
    }                                                                        \
    asm volatile("s_waitcnt lgkmcnt(0)" ::: "memory");                       \
    __builtin_amdgcn_s_barrier();                                            \
  }

  for (int s = 0; s < TT; s += 2){
    STEP(xwA, tkA, s,     0)
    STEP(xwB, tkB, s + 1, 1)
  }
  #undef STEP
  #undef TIDX

  // ---- final h_T / c_T ----
  if (act){
    const size_t O1  = (size_t)BB*TT*(2*HID);
    const size_t idx = (size_t)(b0+q)*HID + u;
    if (dir == 0){
      out[O1                    + idx] = hfin;
      out[O1 +   (size_t)BB*HID + idx] = creg;
    } else {
      out[O1 + 2*(size_t)BB*HID + idx] = hfin;
      out[O1 + 3*(size_t)BB*HID + idx] = creg;
    }
  }
}

extern "C" void kernel_launch(void* const* d_in, const int* in_sizes, int n_in,
                              void* d_out, int out_size, void* d_ws, size_t ws_size,
                              hipStream_t stream)
{
  const int*   tokens = (const int*)  d_in[0];
  const float* emb    = (const float*)d_in[1];
  const float* Wf     = (const float*)d_in[2];
  const float* Ufw    = (const float*)d_in[3];
  const float* bf     = (const float*)d_in[4];
  const float* Wb     = (const float*)d_in[5];
  const float* Ubw    = (const float*)d_in[6];
  const float* bb     = (const float*)d_in[7];
  float* out = (float*)d_out;
  _Float16* EW = (_Float16*)d_ws;     // 30000 x 1024 f16 = 61.44 MB

  embw_mfma<<<dim3((VOCAB + 63)/64, 16), 256, 0, stream>>>(emb, Wf, Wb, bf, bb, EW);
  lstm_r11<<<BB, 512, 0, stream>>>(tokens, EW, Ufw, Ubw, out);
}